// Round 7
// baseline (8426.947 us; speedup 1.0000x reference)
//
#include <hip/hip_runtime.h>
#include <math.h>

// ---------------------------------------------------------------------------
// Tacotron decoder scan, MI355X. Unit-split MFMA pipeline, zero grid barriers,
// per-block flags, minimal cross-XCD payloads (1-4 KB per hop).
// 224 blocks: A(32)=attn-GRU (8 units each), Bp(128)=Bahdanau partials
// (50 enc rows; q0 of each batch also combines+publishes attn), C(32)=
// proj+GRU1, D(32)=GRU2. Weights as split-bf16 LDS-resident images.
// ---------------------------------------------------------------------------

#define TENC 200
#define TDEC 200

typedef short bf16x8 __attribute__((ext_vector_type(8)));
typedef float f32x4  __attribute__((ext_vector_type(4)));

// ---- flag slots (128B line each): FA 0..31, FBsib 32..127 (b*3+s),
// FT 128..159, FC1 160..191, FC2 192..223, FD 224..255
#define O_H1B 8192                       // [2][32][256]
#define O_H2B 24576
#define O_R1B 40960
#define O_AT  57344                      // [2][32][256] final attn
#define O_NPQ 73728                      // [32][3][256] sibling ctx partials
#define O_ZPQ 98304                      // [96] -> pad 128
#define O_PJ  98432                      // [32][256]
#define ZERO_FLOATS 106624
#define O_HAS 106624                     // [200][32][256] h_a stream
#define O_Q2  (O_HAS + 200*32*256)       // [200][32][128]
#define O_WV  (O_Q2 + 200*32*128)        // [32][200][256]
#define O_R2S (O_WV + 32*200*256)        // [200][32][256]
#define O_IMG (O_R2S + 200*32*256)       // ushort images

#define IMGA_OFF  0u                     // [32][2][32][648]
#define IMGC1_OFF 1327104u               // [32][2][16][520]
#define IMGC2_OFF 1859584u               // [32][2][32][520]
#define IMGD_OFF  2924544u               // [32][2][32][520]

__device__ __forceinline__ float sigm(float x)  { return 1.0f / (1.0f + __expf(-x)); }
__device__ __forceinline__ float ftanh(float x) { return 1.0f - 2.0f / (1.0f + __expf(2.0f * x)); }

__device__ __forceinline__ unsigned short f2bf(float f) {
  union { float f; unsigned u; } v; v.f = f;
  return (unsigned short)((v.u + 0x7FFFu + ((v.u >> 16) & 1u)) >> 16);
}
__device__ __forceinline__ float bf2f(unsigned short h) {
  union { unsigned u; float f; } v; v.u = ((unsigned)h) << 16; return v.f;
}

__device__ __forceinline__ void pollwait(const unsigned* p, unsigned tgt, bool act) {
  for (;;) {
    bool ok = true;
    if (act) ok = (__hip_atomic_load(p, __ATOMIC_RELAXED, __HIP_MEMORY_SCOPE_AGENT) >= tgt);
    if (__syncthreads_and((int)ok)) break;
    __builtin_amdgcn_s_sleep(2);
  }
  __builtin_amdgcn_fence(__ATOMIC_ACQUIRE, "agent");
}
__device__ __forceinline__ void set_flag(unsigned* f, unsigned v) {
  __syncthreads();
  if (threadIdx.x == 0) {
    __builtin_amdgcn_fence(__ATOMIC_RELEASE, "agent");
    __hip_atomic_store(f, v, __ATOMIC_RELAXED, __HIP_MEMORY_SCOPE_AGENT);
  }
}

// ---------------------------------------------------------------------------
__global__ __launch_bounds__(256) void k_prep(
    const float* __restrict__ aK, const float* __restrict__ aRK,
    const float* __restrict__ Wp,
    const float* __restrict__ K1, const float* __restrict__ RK1,
    const float* __restrict__ K2, const float* __restrict__ RK2,
    unsigned short* __restrict__ img)
{
  int e = blockIdx.x * 256 + threadIdx.x;
  int id = blockIdx.y;
  float w = 0.f; size_t oh = 0, ol = 0;
  if (id == 0) {
    if (e >= 32*32*648) return;
    int k = e % 648, n = (e / 648) & 31, blk = e / (648*32);
    int u = blk*8 + (n & 7), g = n >> 3;
    if (k < 384) {
      w = (g==0) ? aK[(size_t)k*768+u] : (g==1) ? aK[(size_t)k*768+256+u]
        : (g==2) ? aK[(size_t)k*768+512+u] : 0.f;
    } else if (k < 640) {
      int kk = k - 384;
      w = (g==0) ? aRK[(size_t)kk*768+u] : (g==1) ? aRK[(size_t)kk*768+256+u]
        : (g==3) ? aRK[(size_t)kk*768+512+u] : 0.f;
    }
    size_t base = IMGA_OFF + (size_t)blk*2*32*648;
    oh = base + (size_t)n*648 + k; ol = oh + 32*648;
  } else if (id == 1) {
    if (e >= 32*16*520) return;
    int k = e % 520, n = (e / 520) & 15, blk = e / (520*16);
    if (n < 8 && k < 512) w = Wp[(size_t)k*256 + blk*8 + n];
    size_t base = IMGC1_OFF + (size_t)blk*2*16*520;
    oh = base + (size_t)n*520 + k; ol = oh + 16*520;
  } else {
    if (e >= 32*32*520) return;
    int k = e % 520, n = (e / 520) & 31, blk = e / (520*32);
    int u = blk*8 + (n & 7), g = n >> 3;
    const float* Kx = (id == 2) ? K1 : K2;
    const float* Rx = (id == 2) ? RK1 : RK2;
    if (k < 256) {
      w = (g==0) ? Kx[(size_t)k*768+u] : (g==1) ? Kx[(size_t)k*768+256+u]
        : (g==2) ? Kx[(size_t)k*768+512+u] : 0.f;
    } else if (k < 512) {
      int kk = k - 256;
      w = (g==0) ? Rx[(size_t)kk*768+u] : (g==1) ? Rx[(size_t)kk*768+256+u]
        : (g==3) ? Rx[(size_t)kk*768+512+u] : 0.f;
    }
    size_t base = ((id == 2) ? IMGC2_OFF : IMGD_OFF) + (size_t)blk*2*32*520;
    oh = base + (size_t)n*520 + k; ol = oh + 32*520;
  }
  unsigned short hi = f2bf(w);
  unsigned short lo = f2bf(w - bf2f(hi));
  img[oh] = hi; img[ol] = lo;
}

// ---------------------------------------------------------------------------
__global__ __launch_bounds__(256, 1) void k_scan7(
    const float* __restrict__ memg,
    const float* __restrict__ aB, const float* __restrict__ Uw,
    const float* __restrict__ Vw, const float* __restrict__ pb,
    const float* __restrict__ B1v, const float* __restrict__ B2v,
    float* __restrict__ ws)
{
  const int tid = threadIdx.x, bid = blockIdx.x;
  const int lane = tid & 63, wv = tid >> 6;
  unsigned* fl = (unsigned*)ws;
  float* fH1B = ws + O_H1B;  float* fH2B = ws + O_H2B;  float* fR1B = ws + O_R1B;
  float* fAT  = ws + O_AT;   float* fNPq = ws + O_NPQ;  float* fZPq = ws + O_ZPQ;
  float* fPJ  = ws + O_PJ;   float* fHAS = ws + O_HAS;
  float* fQ2  = ws + O_Q2;   float* fWV  = ws + O_WV;   float* fR2S = ws + O_R2S;
  const unsigned short* img = (const unsigned short*)(ws + O_IMG);

  __shared__ __align__(16) char smem[140544];

  if (bid < 32) {
    // ================= stage A: attn-GRU (8 units each) ====================
    const int j = bid;
    unsigned* myflag = fl + j * 32;
    unsigned short* sW = (unsigned short*)smem;            // [2][32][648]
    unsigned short* sX = (unsigned short*)(smem + 82944);  // [32][648]
    float* sOut = (float*)(smem + 124416);                 // [32][36]
    float* sHP  = (float*)(smem + 129024);                 // [32][8]
    float* sB   = (float*)(smem + 130048);                 // [4][8]
    {
      const uint4* src = (const uint4*)(img + IMGA_OFF + (size_t)j*2*32*648);
      uint4* dst = (uint4*)sW;
      for (int i = tid; i < 82944/16; i += 256) dst[i] = src[i];
      if (tid < 8) {
        int u = j*8 + tid;
        sB[tid]      = aB[u]       + aB[768 + u];
        sB[8 + tid]  = aB[256 + u] + aB[1024 + u];
        sB[16 + tid] = aB[512 + u];
        sB[24 + tid] = aB[1280 + u];
      }
    }
    __syncthreads();
    for (int t = 0; t < TDEC; ++t) {
      for (int i = tid; i < 4096; i += 256) {           // q (indep of deps)
        int b = i >> 7, k = i & 127;
        sX[b*648 + k] = f2bf(fQ2[((size_t)t*32 + b)*128 + k]);
      }
      // wait: final attn(t-1) published by all 32 q0 blocks
      pollwait(fl + (128 + (tid & 31))*32, (unsigned)t, (t > 0) && (tid < 32));
      const float* at = fAT + (size_t)((t-1) & 1)*8192;
      for (int i = tid; i < 8192; i += 256) {           // attn(t-1)
        int b = i >> 8, d = i & 255;
        float v = (t > 0) ? at[b*256 + d] : 0.f;
        sX[b*648 + 128 + d] = f2bf(v);
      }
      for (int i = tid; i < 8192; i += 256) {           // h_a(t-1)
        int b = i >> 8, d = i & 255;
        float v = (t > 0) ? fHAS[((size_t)(t-1)*32 + b)*256 + d] : 0.f;
        sX[b*648 + 384 + d] = f2bf(v);
      }
      { int b = tid >> 3, ul = tid & 7;
        sHP[tid] = (t > 0) ? fHAS[((size_t)(t-1)*32 + b)*256 + j*8 + ul] : 0.f; }
      __syncthreads();
      { // GEMM [32x640]@[640x32]
        const int mt = wv >> 1, nt = wv & 1;
        f32x4 acc = {0.f, 0.f, 0.f, 0.f};
        const unsigned short* xr = sX + (size_t)(mt*16 + (lane&15))*648 + ((lane>>4)*8);
        const unsigned short* wh = sW + (size_t)(nt*16 + (lane&15))*648 + ((lane>>4)*8);
        const unsigned short* wl = wh + 32*648;
        for (int kt = 0; kt < 20; ++kt) {
          bf16x8 a  = *(const bf16x8*)(xr + kt*32);
          bf16x8 bh = *(const bf16x8*)(wh + kt*32);
          bf16x8 bl = *(const bf16x8*)(wl + kt*32);
          acc = __builtin_amdgcn_mfma_f32_16x16x32_bf16(a, bh, acc, 0, 0, 0);
          acc = __builtin_amdgcn_mfma_f32_16x16x32_bf16(a, bl, acc, 0, 0, 0);
        }
        int r0 = mt*16 + ((lane>>4)<<2), c = nt*16 + (lane&15);
        #pragma unroll
        for (int i2 = 0; i2 < 4; ++i2) sOut[(r0+i2)*36 + c] = acc[i2];
      }
      __syncthreads();
      { int b = tid >> 3, ul = tid & 7;
        float z = sigm(sOut[b*36 + ul] + sB[ul]);
        float r = sigm(sOut[b*36 + 8 + ul] + sB[8+ul]);
        float hh = ftanh(sOut[b*36 + 16 + ul] + sB[16+ul] + r*(sOut[b*36 + 24 + ul] + sB[24+ul]));
        float hn = z * sHP[tid] + (1.0f - z) * hh;
        fHAS[((size_t)t*32 + b)*256 + j*8 + ul] = hn;
      }
      set_flag(myflag, (unsigned)(t + 1));   // only 1KB to drain
    }
  } else if (bid < 160) {
    // ========== stage Bp: attention partials; q0 combines+publishes ========
    const int idx = bid - 32, b = idx >> 2, q = idx & 3;
    unsigned* myflag = fl + (32 + b*3 + (q - 1)) * 32;   // only used when q>0
    float* sWV  = (float*)smem;            // [50][260]
    float* sMem = (float*)(smem + 52000);  // [50][260]
    float* sV   = (float*)(smem + 104000); // [256]
    float* sHA  = (float*)(smem + 105024); // [256]
    float* sUh  = (float*)(smem + 106048); // [256]
    float* sE   = (float*)(smem + 107072); // [64]
    float* sZ   = (float*)(smem + 107328); // [1]
    float* sCtx = (float*)(smem + 107392); // [256]
    float* sZs  = (float*)(smem + 108416); // [4]
    for (int i = tid; i < 50*256; i += 256) {
      int r = i >> 8, d = i & 255;
      sWV[r*260 + d]  = fWV[((size_t)b*200 + q*50 + r)*256 + d];
      sMem[r*260 + d] = memg[((size_t)b*200 + q*50 + r)*256 + d];
    }
    sV[tid] = Vw[tid];
    __syncthreads();
    for (int t = 0; t < TDEC; ++t) {
      pollwait(fl + (tid & 31)*32, (unsigned)(t + 1), tid < 32);   // A(t) done
      sHA[tid] = fHAS[((size_t)t*32 + b)*256 + tid];
      __syncthreads();
      { // Uh = h_a[b] @ U  (U streams from local L2, coalesced)
        float acc = 0.f;
        #pragma unroll 8
        for (int k = 0; k < 256; ++k) acc += sHA[k] * Uw[(size_t)k*256 + tid];
        sUh[tid] = acc; }
      __syncthreads();
      { int r = tid >> 2, qd = tid & 3;
        float part = 0.f;
        if (r < 50) {
          const float* wvp = sWV + r*260 + qd*64;
          const float* uh = sUh + qd*64;
          const float* vv = sV + qd*64;
          #pragma unroll 8
          for (int i2 = 0; i2 < 64; ++i2) part += vv[i2] * ftanh(wvp[i2] + uh[i2]);
        }
        part += __shfl_down(part, 2, 4);
        part += __shfl_down(part, 1, 4);
        if (r < 50 && qd == 0) sE[r] = __expf(part);   // max-free: scores bounded
      }
      __syncthreads();
      if (tid < 64) {
        float e = (tid < 50) ? sE[tid] : 0.f;
        #pragma unroll
        for (int off = 32; off; off >>= 1) e += __shfl_xor(e, off, 64);
        if (tid == 0) sZ[0] = e;
      }
      __syncthreads();
      { float acc = 0.f;
        #pragma unroll 2
        for (int r = 0; r < 50; ++r) acc += sE[r] * sMem[r*260 + tid];
        if (q) fNPq[((size_t)b*3 + q - 1)*256 + tid] = acc;
        else   sCtx[tid] = acc; }
      if (q) {
        if (tid == 0) fZPq[b*3 + q - 1] = sZ[0];
        set_flag(myflag, (unsigned)(t + 1));
      } else {
        // combine: wait 3 siblings(t); fAT slot overwrite gated by C1 >= t-1
        { const unsigned* p; unsigned tg; bool act;
          if (tid < 3)                    { p = fl + (32 + b*3 + tid)*32; tg = (unsigned)(t+1); act = true; }
          else if (tid >= 32 && tid < 64) { p = fl + (160 + tid - 32)*32; tg = (unsigned)(t-1); act = (t >= 2); }
          else                            { p = fl;                       tg = 0u;              act = false; }
          pollwait(p, tg, act);
        }
        if (tid < 3) sZs[tid] = fZPq[b*3 + tid];
        __syncthreads();
        float Zi = 1.0f / (sZ[0] + sZs[0] + sZs[1] + sZs[2]);
        float av = (sCtx[tid] + fNPq[(size_t)(b*3 + 0)*256 + tid]
                             + fNPq[(size_t)(b*3 + 1)*256 + tid]
                             + fNPq[(size_t)(b*3 + 2)*256 + tid]) * Zi;
        fAT[(size_t)(t & 1)*8192 + b*256 + tid] = av;
        set_flag(fl + (128 + b)*32, (unsigned)(t + 1));
      }
    }
  } else if (bid < 192) {
    // ================= stage C: proj + GRU1 (8 units) ======================
    const int j = bid - 160;
    unsigned* flagC1 = fl + (160 + j) * 32;
    unsigned* flagC2 = fl + (192 + j) * 32;
    unsigned short* sW1 = (unsigned short*)smem;            // [2][16][520]
    unsigned short* sW2 = (unsigned short*)(smem + 33280);  // [2][32][520]
    unsigned short* sX  = (unsigned short*)(smem + 99840);  // [32][520]
    float* sOut = (float*)(smem + 133120);                  // [32][36]
    float* sPJ  = (float*)(smem + 137728);                  // [32][8]
    float* sH1p = (float*)(smem + 138752);                  // [32][8]
    float* sB   = (float*)(smem + 139776);                  // [5][8]
    {
      const uint4* s1 = (const uint4*)(img + IMGC1_OFF + (size_t)j*2*16*520);
      uint4* d1 = (uint4*)sW1;
      for (int i = tid; i < 33280/16; i += 256) d1[i] = s1[i];
      const uint4* s2 = (const uint4*)(img + IMGC2_OFF + (size_t)j*2*32*520);
      uint4* d2 = (uint4*)sW2;
      for (int i = tid; i < 66560/16; i += 256) d2[i] = s2[i];
      if (tid < 8) {
        int u = j*8 + tid;
        sB[tid]      = B1v[u]       + B1v[768 + u];
        sB[8 + tid]  = B1v[256 + u] + B1v[1024 + u];
        sB[16 + tid] = B1v[512 + u];
        sB[24 + tid] = B1v[1280 + u];
        sB[32 + tid] = pb[u];
      }
    }
    __syncthreads();
    for (int t = 0; t < TDEC; ++t) {
      { // wait: attn(t) final; C2 >= t (fPJ/h1 safety); D >= t-1 (r1 parity)
        const unsigned* p; unsigned tg; bool act;
        if (tid < 32)      { p = fl + (128 + tid)*32;       tg = (unsigned)(t+1); act = true; }
        else if (tid < 64) { p = fl + (192 + tid - 32)*32;  tg = (unsigned)t;     act = (t > 0); }
        else if (tid < 96) { p = fl + (224 + tid - 64)*32;  tg = (unsigned)(t-1); act = (t >= 2); }
        else               { p = fl;                        tg = 0u;              act = false; }
        pollwait(p, tg, act);
      }
      const float* at = fAT + (size_t)(t & 1)*8192;
      for (int i = tid; i < 8192; i += 256) {           // attn(t)
        int b = i >> 8, d = i & 255;
        sX[b*520 + d] = f2bf(at[b*256 + d]);
      }
      for (int i = tid; i < 8192; i += 256) {           // h_a(t)
        int b = i >> 8, d = i & 255;
        sX[b*520 + 256 + d] = f2bf(fHAS[((size_t)t*32 + b)*256 + d]);
      }
      __syncthreads();
      if (wv < 2) { // GEMM proj: [32x512]@[512x16(8 valid)]
        const int mt = wv;
        f32x4 acc = {0.f, 0.f, 0.f, 0.f};
        const unsigned short* xr = sX + (size_t)(mt*16 + (lane&15))*520 + ((lane>>4)*8);
        const unsigned short* wh = sW1 + (size_t)(lane&15)*520 + ((lane>>4)*8);
        const unsigned short* wl = wh + 16*520;
        for (int kt = 0; kt < 16; ++kt) {
          bf16x8 a  = *(const bf16x8*)(xr + kt*32);
          bf16x8 bh = *(const bf16x8*)(wh + kt*32);
          bf16x8 bl = *(const bf16x8*)(wl + kt*32);
          acc = __builtin_amdgcn_mfma_f32_16x16x32_bf16(a, bh, acc, 0, 0, 0);
          acc = __builtin_amdgcn_mfma_f32_16x16x32_bf16(a, bl, acc, 0, 0, 0);
        }
        int r0 = mt*16 + ((lane>>4)<<2), c = lane & 15;
        #pragma unroll
        for (int i2 = 0; i2 < 4; ++i2) sOut[(r0+i2)*36 + c] = acc[i2];
      }
      __syncthreads();
      { int b = tid >> 3, ul = tid & 7;
        float pj = sOut[b*36 + ul] + sB[32 + ul];
        sPJ[tid] = pj;
        fPJ[(size_t)b*256 + j*8 + ul] = pj; }
      set_flag(flagC1, (unsigned)(t + 1));
      pollwait(fl + (160 + (tid & 31))*32, (unsigned)(t + 1), tid < 32);
      for (int i = tid; i < 8192; i += 256) {           // proj(t) full
        int b = i >> 8, d = i & 255;
        sX[b*520 + d] = f2bf(fPJ[(size_t)b*256 + d]);
      }
      for (int i = tid; i < 8192; i += 256) {           // h1(t-1)
        int b = i >> 8, d = i & 255;
        sX[b*520 + 256 + d] = f2bf(fH1B[(size_t)(t & 1)*8192 + (size_t)b*256 + d]);
      }
      { int b = tid >> 3, ul = tid & 7;
        sH1p[tid] = fH1B[(size_t)(t & 1)*8192 + (size_t)b*256 + j*8 + ul]; }
      __syncthreads();
      { // GEMM GRU1
        const int mt = wv >> 1, nt = wv & 1;
        f32x4 acc = {0.f, 0.f, 0.f, 0.f};
        const unsigned short* xr = sX + (size_t)(mt*16 + (lane&15))*520 + ((lane>>4)*8);
        const unsigned short* wh = sW2 + (size_t)(nt*16 + (lane&15))*520 + ((lane>>4)*8);
        const unsigned short* wl = wh + 32*520;
        for (int kt = 0; kt < 16; ++kt) {
          bf16x8 a  = *(const bf16x8*)(xr + kt*32);
          bf16x8 bh = *(const bf16x8*)(wh + kt*32);
          bf16x8 bl = *(const bf16x8*)(wl + kt*32);
          acc = __builtin_amdgcn_mfma_f32_16x16x32_bf16(a, bh, acc, 0, 0, 0);
          acc = __builtin_amdgcn_mfma_f32_16x16x32_bf16(a, bl, acc, 0, 0, 0);
        }
        int r0 = mt*16 + ((lane>>4)<<2), c = nt*16 + (lane&15);
        #pragma unroll
        for (int i2 = 0; i2 < 4; ++i2) sOut[(r0+i2)*36 + c] = acc[i2];
      }
      __syncthreads();
      { int b = tid >> 3, ul = tid & 7;
        float z = sigm(sOut[b*36 + ul] + sB[ul]);
        float r = sigm(sOut[b*36 + 8 + ul] + sB[8+ul]);
        float hh = ftanh(sOut[b*36 + 16 + ul] + sB[16+ul] + r*(sOut[b*36 + 24 + ul] + sB[24+ul]));
        float hn = z * sH1p[tid] + (1.0f - z) * hh;
        fH1B[(size_t)((t+1) & 1)*8192 + (size_t)b*256 + j*8 + ul] = hn;
        fR1B[(size_t)(t & 1)*8192 + (size_t)b*256 + j*8 + ul] = sPJ[tid] + hn;
      }
      set_flag(flagC2, (unsigned)(t + 1));
    }
  } else {
    // ================= stage D: GRU2 (8 units) =============================
    const int j = bid - 192;
    unsigned* myflag = fl + (224 + j) * 32;
    unsigned short* sW = (unsigned short*)smem;            // [2][32][520]
    unsigned short* sX = (unsigned short*)(smem + 66560);  // [32][520]
    float* sOut = (float*)(smem + 99840);                  // [32][36]
    float* sR1f = (float*)(smem + 104448);                 // [32][8]
    float* sH2p = (float*)(smem + 105472);                 // [32][8]
    float* sB   = (float*)(smem + 106496);                 // [4][8]
    {
      const uint4* s2 = (const uint4*)(img + IMGD_OFF + (size_t)j*2*32*520);
      uint4* d2 = (uint4*)sW;
      for (int i = tid; i < 66560/16; i += 256) d2[i] = s2[i];
      if (tid < 8) {
        int u = j*8 + tid;
        sB[tid]      = B2v[u]       + B2v[768 + u];
        sB[8 + tid]  = B2v[256 + u] + B2v[1024 + u];
        sB[16 + tid] = B2v[512 + u];
        sB[24 + tid] = B2v[1280 + u];
      }
    }
    __syncthreads();
    for (int t = 0; t < TDEC; ++t) {
      { const unsigned* p; unsigned tg; bool act;
        if (tid < 32)      { p = fl + (192 + tid)*32;       tg = (unsigned)(t+1); act = true; }
        else if (tid < 64) { p = fl + (224 + tid - 32)*32;  tg = (unsigned)t;     act = (t > 0); }
        else               { p = fl;                        tg = 0u;              act = false; }
        pollwait(p, tg, act);
      }
      for (int i = tid; i < 8192; i += 256) {           // r1(t)
        int b = i >> 8, d = i & 255;
        sX[b*520 + d] = f2bf(fR1B[(size_t)(t & 1)*8192 + (size_t)b*256 + d]);
      }
      for (int i = tid; i < 8192; i += 256) {           // h2(t-1)
        int b = i >> 8, d = i & 255;
        sX[b*520 + 256 + d] = f2bf(fH2B[(size_t)(t & 1)*8192 + (size_t)b*256 + d]);
      }
      { int b = tid >> 3, ul = tid & 7;
        sR1f[tid] = fR1B[(size_t)(t & 1)*8192 + (size_t)b*256 + j*8 + ul];
        sH2p[tid] = fH2B[(size_t)(t & 1)*8192 + (size_t)b*256 + j*8 + ul]; }
      __syncthreads();
      { const int mt = wv >> 1, nt = wv & 1;
        f32x4 acc = {0.f, 0.f, 0.f, 0.f};
        const unsigned short* xr = sX + (size_t)(mt*16 + (lane&15))*520 + ((lane>>4)*8);
        const unsigned short* wh = sW + (size_t)(nt*16 + (lane&15))*520 + ((lane>>4)*8);
        const unsigned short* wl = wh + 32*520;
        for (int kt = 0; kt < 16; ++kt) {
          bf16x8 a  = *(const bf16x8*)(xr + kt*32);
          bf16x8 bh = *(const bf16x8*)(wh + kt*32);
          bf16x8 bl = *(const bf16x8*)(wl + kt*32);
          acc = __builtin_amdgcn_mfma_f32_16x16x32_bf16(a, bh, acc, 0, 0, 0);
          acc = __builtin_amdgcn_mfma_f32_16x16x32_bf16(a, bl, acc, 0, 0, 0);
        }
        int r0 = mt*16 + ((lane>>4)<<2), c = nt*16 + (lane&15);
        #pragma unroll
        for (int i2 = 0; i2 < 4; ++i2) sOut[(r0+i2)*36 + c] = acc[i2];
      }
      __syncthreads();
      { int b = tid >> 3, ul = tid & 7;
        float z = sigm(sOut[b*36 + ul] + sB[ul]);
        float r = sigm(sOut[b*36 + 8 + ul] + sB[8+ul]);
        float hh = ftanh(sOut[b*36 + 16 + ul] + sB[16+ul] + r*(sOut[b*36 + 24 + ul] + sB[24+ul]));
        float hn = z * sH2p[tid] + (1.0f - z) * hh;
        fH2B[(size_t)((t+1) & 1)*8192 + (size_t)b*256 + j*8 + ul] = hn;
        fR2S[((size_t)t*32 + b)*256 + j*8 + ul] = sR1f[tid] + hn;
      }
      set_flag(myflag, (unsigned)(t + 1));
    }
  }
}

// ---------------------------------------------------------------------------
__global__ __launch_bounds__(256) void k_wv(
    const float* __restrict__ mem, const float* __restrict__ W, float* __restrict__ wv)
{
  const int tile = blockIdx.x, b = blockIdx.y;
  const int t0 = tile * 8, tid = threadIdx.x;
  __shared__ float rows[2048];
  for (int i = tid; i < 2048; i += 256) rows[i] = mem[((size_t)b*TENC + t0)*256 + i];
  __syncthreads();
  float acc[8] = {0,0,0,0,0,0,0,0};
  for (int k = 0; k < 256; ++k) {
    float w = W[(size_t)k*256 + tid];
    #pragma unroll
    for (int tt = 0; tt < 8; ++tt) acc[tt] += rows[tt*256 + k] * w;
  }
  #pragma unroll
  for (int tt = 0; tt < 8; ++tt) wv[((size_t)b*TENC + t0 + tt)*256 + tid] = acc[tt];
}

__global__ __launch_bounds__(256) void k_prenet(
    const float* __restrict__ x, const float* __restrict__ w1, const float* __restrict__ b1,
    const float* __restrict__ w2, const float* __restrict__ b2, float* __restrict__ q2)
{
  const int tile = blockIdx.x, b = blockIdx.y;
  const int t0 = tile * 4, tid = threadIdx.x;
  __shared__ float xr[320];
  __shared__ float q1[1024];
  for (int i = tid; i < 320; i += 256) {
    int tt = i / 80, k = i - tt*80;
    xr[i] = x[((size_t)b*TDEC + t0 + tt)*80 + k];
  }
  __syncthreads();
  {
    float a0 = 0.f, a1 = 0.f, a2 = 0.f, a3 = 0.f;
    for (int k = 0; k < 80; ++k) {
      float w = w1[(size_t)k*256 + tid];
      a0 += xr[k]*w; a1 += xr[80+k]*w; a2 += xr[160+k]*w; a3 += xr[240+k]*w;
    }
    float bb = b1[tid];
    q1[tid]       = fmaxf(a0 + bb, 0.f);
    q1[256 + tid] = fmaxf(a1 + bb, 0.f);
    q1[512 + tid] = fmaxf(a2 + bb, 0.f);
    q1[768 + tid] = fmaxf(a3 + bb, 0.f);
  }
  __syncthreads();
  {
    const int jj = tid & 127, tp = tid >> 7;
    float c0 = 0.f, c1 = 0.f;
    for (int k = 0; k < 256; ++k) {
      float w = w2[(size_t)k*128 + jj];
      c0 += q1[(2*tp)*256 + k] * w;
      c1 += q1[(2*tp + 1)*256 + k] * w;
    }
    float bb = b2[jj];
    q2[(((size_t)t0 + 2*tp)*32 + b)*128 + jj]     = fmaxf(c0 + bb, 0.f);
    q2[(((size_t)t0 + 2*tp + 1)*32 + b)*128 + jj] = fmaxf(c1 + bb, 0.f);
  }
}

__global__ __launch_bounds__(128) void k_out(
    const float* __restrict__ r2, const float* __restrict__ wo,
    const float* __restrict__ bo, float* __restrict__ out)
{
  const int tb = blockIdx.x;
  const int t = tb >> 5, b = tb & 31, tid = threadIdx.x;
  __shared__ float row[256];
  for (int i = tid; i < 256; i += 128) row[i] = r2[(size_t)tb*256 + i];
  __syncthreads();
  if (tid < 80) {
    float acc = bo[tid];
    #pragma unroll 4
    for (int k = 0; k < 256; ++k) acc += row[k] * wo[(size_t)k*80 + tid];
    out[((size_t)b*TDEC + t)*80 + tid] = acc;
  }
}

// ---------------------------------------------------------------------------
extern "C" void kernel_launch(void* const* d_in, const int* in_sizes, int n_in,
                              void* d_out, int out_size, void* d_ws, size_t ws_size,
                              hipStream_t stream)
{
  const float* mem = (const float*)d_in[0];
  const float* dec = (const float*)d_in[1];
  const float* w1  = (const float*)d_in[2];
  const float* b1  = (const float*)d_in[3];
  const float* w2  = (const float*)d_in[4];
  const float* b2  = (const float*)d_in[5];
  const float* aK  = (const float*)d_in[6];
  const float* aRK = (const float*)d_in[7];
  const float* aB  = (const float*)d_in[8];
  const float* W   = (const float*)d_in[9];
  const float* U   = (const float*)d_in[10];
  const float* V   = (const float*)d_in[11];
  const float* Wp  = (const float*)d_in[12];
  const float* pb  = (const float*)d_in[13];
  const float* K1  = (const float*)d_in[14];
  const float* RK1 = (const float*)d_in[15];
  const float* B1v = (const float*)d_in[16];
  const float* K2  = (const float*)d_in[17];
  const float* RK2 = (const float*)d_in[18];
  const float* B2v = (const float*)d_in[19];
  const float* Wo  = (const float*)d_in[20];
  const float* bo  = (const float*)d_in[21];
  float* ws  = (float*)d_ws;
  float* out = (float*)d_out;

  hipMemsetAsync(ws, 0, (size_t)ZERO_FLOATS * sizeof(float), stream);
  k_prep<<<dim3(2592, 4), 256, 0, stream>>>(aK, aRK, Wp, K1, RK1, K2, RK2,
                                            (unsigned short*)(ws + O_IMG));
  k_wv<<<dim3(25, 32), 256, 0, stream>>>(mem, W, ws + O_WV);
  k_prenet<<<dim3(50, 32), 256, 0, stream>>>(dec, w1, b1, w2, b2, ws + O_Q2);
  k_scan7<<<224, 256, 0, stream>>>(mem, aB, U, V, pb, B1v, B2v, ws);
  k_out<<<6400, 128, 0, stream>>>(ws + O_R2S, Wo, bo, out);
}

// Round 8
// 6461.189 us; speedup vs baseline: 1.3042x; 1.3042x over previous
//
#include <hip/hip_runtime.h>
#include <math.h>

// ---------------------------------------------------------------------------
// Tacotron decoder scan, MI355X. Unit-split MFMA pipeline, zero grid barriers.
// R8: SAME dataflow/flag graph as R7, but fence-free MALL-coherent messaging:
// cross-block payloads use relaxed agent-scope atomics (bypass non-coherent
// per-XCD L2s); publish = s_waitcnt drain + flag store; NO acquire/release
// fences -> read-only data stays L2-hot, no L2 writeback/invalidate storms.
// 224 blocks: A(32)=attn-GRU, Bp(128)=Bahdanau partials (q0 combines),
// C(32)=proj+GRU1, D(32)=GRU2. Weights as split-bf16 LDS-resident images.
// ---------------------------------------------------------------------------

#define TENC 200
#define TDEC 200

typedef short bf16x8 __attribute__((ext_vector_type(8)));
typedef float f32x4  __attribute__((ext_vector_type(4)));

// ---- flag slots (128B line each): FA 0..31, FBsib 32..127 (b*3+s),
// FT 128..159, FC1 160..191, FC2 192..223, FD 224..255
#define O_H1B 8192                       // [2][32][256]
#define O_H2B 24576
#define O_R1B 40960
#define O_AT  57344                      // [2][32][256] final attn
#define O_NPQ 73728                      // [32][3][256] sibling ctx partials
#define O_ZPQ 98304                      // [96] -> pad 128
#define O_PJ  98432                      // [32][256]
#define ZERO_FLOATS 106624
#define O_HAS 106624                     // [200][32][256] h_a stream
#define O_Q2  (O_HAS + 200*32*256)       // [200][32][128]
#define O_WV  (O_Q2 + 200*32*128)        // [32][200][256]
#define O_R2S (O_WV + 32*200*256)        // [200][32][256]
#define O_IMG (O_R2S + 200*32*256)       // ushort images

#define IMGA_OFF  0u                     // [32][2][32][648]
#define IMGC1_OFF 1327104u               // [32][2][16][520]
#define IMGC2_OFF 1859584u               // [32][2][32][520]
#define IMGD_OFF  2924544u               // [32][2][32][520]

__device__ __forceinline__ float sigm(float x)  { return 1.0f / (1.0f + __expf(-x)); }
__device__ __forceinline__ float ftanh(float x) { return 1.0f - 2.0f / (1.0f + __expf(2.0f * x)); }

__device__ __forceinline__ unsigned short f2bf(float f) {
  union { float f; unsigned u; } v; v.f = f;
  return (unsigned short)((v.u + 0x7FFFu + ((v.u >> 16) & 1u)) >> 16);
}
__device__ __forceinline__ float bf2f(unsigned short h) {
  union { unsigned u; float f; } v; v.u = ((unsigned)h) << 16; return v.f;
}

// MALL-coherent (L2-bypassing) accesses for cross-block payloads.
__device__ __forceinline__ void gst(float* p, float v) {
  __hip_atomic_store(p, v, __ATOMIC_RELAXED, __HIP_MEMORY_SCOPE_AGENT);
}
__device__ __forceinline__ float gld(const float* p) {
  return __hip_atomic_load(p, __ATOMIC_RELAXED, __HIP_MEMORY_SCOPE_AGENT);
}

// poll: relaxed loads (already coherent at MALL); NO cache-invalidate fence.
__device__ __forceinline__ void pollwait(const unsigned* p, unsigned tgt, bool act) {
  for (;;) {
    bool ok = true;
    if (act) ok = (__hip_atomic_load(p, __ATOMIC_RELAXED, __HIP_MEMORY_SCOPE_AGENT) >= tgt);
    if (__syncthreads_and((int)ok)) break;
    __builtin_amdgcn_s_sleep(2);
  }
  asm volatile("" ::: "memory");   // compiler-only ordering
}
// publish: drain own stores (vmcnt->MALL ack), barrier, then flag store.
__device__ __forceinline__ void set_flag(unsigned* f, unsigned v) {
  asm volatile("" ::: "memory");
  __builtin_amdgcn_s_waitcnt(0);
  __syncthreads();
  if (threadIdx.x == 0) {
    __hip_atomic_store(f, v, __ATOMIC_RELAXED, __HIP_MEMORY_SCOPE_AGENT);
  }
}

// ---------------------------------------------------------------------------
__global__ __launch_bounds__(256) void k_prep(
    const float* __restrict__ aK, const float* __restrict__ aRK,
    const float* __restrict__ Wp,
    const float* __restrict__ K1, const float* __restrict__ RK1,
    const float* __restrict__ K2, const float* __restrict__ RK2,
    unsigned short* __restrict__ img)
{
  int e = blockIdx.x * 256 + threadIdx.x;
  int id = blockIdx.y;
  float w = 0.f; size_t oh = 0, ol = 0;
  if (id == 0) {
    if (e >= 32*32*648) return;
    int k = e % 648, n = (e / 648) & 31, blk = e / (648*32);
    int u = blk*8 + (n & 7), g = n >> 3;
    if (k < 384) {
      w = (g==0) ? aK[(size_t)k*768+u] : (g==1) ? aK[(size_t)k*768+256+u]
        : (g==2) ? aK[(size_t)k*768+512+u] : 0.f;
    } else if (k < 640) {
      int kk = k - 384;
      w = (g==0) ? aRK[(size_t)kk*768+u] : (g==1) ? aRK[(size_t)kk*768+256+u]
        : (g==3) ? aRK[(size_t)kk*768+512+u] : 0.f;
    }
    size_t base = IMGA_OFF + (size_t)blk*2*32*648;
    oh = base + (size_t)n*648 + k; ol = oh + 32*648;
  } else if (id == 1) {
    if (e >= 32*16*520) return;
    int k = e % 520, n = (e / 520) & 15, blk = e / (520*16);
    if (n < 8 && k < 512) w = Wp[(size_t)k*256 + blk*8 + n];
    size_t base = IMGC1_OFF + (size_t)blk*2*16*520;
    oh = base + (size_t)n*520 + k; ol = oh + 16*520;
  } else {
    if (e >= 32*32*520) return;
    int k = e % 520, n = (e / 520) & 31, blk = e / (520*32);
    int u = blk*8 + (n & 7), g = n >> 3;
    const float* Kx = (id == 2) ? K1 : K2;
    const float* Rx = (id == 2) ? RK1 : RK2;
    if (k < 256) {
      w = (g==0) ? Kx[(size_t)k*768+u] : (g==1) ? Kx[(size_t)k*768+256+u]
        : (g==2) ? Kx[(size_t)k*768+512+u] : 0.f;
    } else if (k < 512) {
      int kk = k - 256;
      w = (g==0) ? Rx[(size_t)kk*768+u] : (g==1) ? Rx[(size_t)kk*768+256+u]
        : (g==3) ? Rx[(size_t)kk*768+512+u] : 0.f;
    }
    size_t base = ((id == 2) ? IMGC2_OFF : IMGD_OFF) + (size_t)blk*2*32*520;
    oh = base + (size_t)n*520 + k; ol = oh + 32*520;
  }
  unsigned short hi = f2bf(w);
  unsigned short lo = f2bf(w - bf2f(hi));
  img[oh] = hi; img[ol] = lo;
}

// ---------------------------------------------------------------------------
__global__ __launch_bounds__(256, 1) void k_scan8(
    const float* __restrict__ memg,
    const float* __restrict__ aB, const float* __restrict__ Uw,
    const float* __restrict__ Vw, const float* __restrict__ pb,
    const float* __restrict__ B1v, const float* __restrict__ B2v,
    float* __restrict__ ws)
{
  const int tid = threadIdx.x, bid = blockIdx.x;
  const int lane = tid & 63, wv = tid >> 6;
  unsigned* fl = (unsigned*)ws;
  float* fH1B = ws + O_H1B;  float* fH2B = ws + O_H2B;  float* fR1B = ws + O_R1B;
  float* fAT  = ws + O_AT;   float* fNPq = ws + O_NPQ;  float* fZPq = ws + O_ZPQ;
  float* fPJ  = ws + O_PJ;   float* fHAS = ws + O_HAS;
  float* fQ2  = ws + O_Q2;   float* fWV  = ws + O_WV;   float* fR2S = ws + O_R2S;
  const unsigned short* img = (const unsigned short*)(ws + O_IMG);

  __shared__ __align__(16) char smem[140544];

  if (bid < 32) {
    // ================= stage A: attn-GRU (8 units each) ====================
    const int j = bid;
    unsigned* myflag = fl + j * 32;
    unsigned short* sW = (unsigned short*)smem;            // [2][32][648]
    unsigned short* sX = (unsigned short*)(smem + 82944);  // [32][648]
    float* sOut = (float*)(smem + 124416);                 // [32][36]
    float* sHP  = (float*)(smem + 129024);                 // [32][8]
    float* sB   = (float*)(smem + 130048);                 // [4][8]
    {
      const uint4* src = (const uint4*)(img + IMGA_OFF + (size_t)j*2*32*648);
      uint4* dst = (uint4*)sW;
      for (int i = tid; i < 82944/16; i += 256) dst[i] = src[i];
      if (tid < 8) {
        int u = j*8 + tid;
        sB[tid]      = aB[u]       + aB[768 + u];
        sB[8 + tid]  = aB[256 + u] + aB[1024 + u];
        sB[16 + tid] = aB[512 + u];
        sB[24 + tid] = aB[1280 + u];
      }
    }
    __syncthreads();
    for (int t = 0; t < TDEC; ++t) {
      for (int i = tid; i < 4096; i += 256) {           // q (read-only, L2-hot)
        int b = i >> 7, k = i & 127;
        sX[b*648 + k] = f2bf(fQ2[((size_t)t*32 + b)*128 + k]);
      }
      // wait: final attn(t-1) published by all 32 q0 blocks
      pollwait(fl + (128 + (tid & 31))*32, (unsigned)t, (t > 0) && (tid < 32));
      float* at = fAT + (size_t)((t-1) & 1)*8192;
      for (int i = tid; i < 8192; i += 256) {           // attn(t-1)
        int b = i >> 8, d = i & 255;
        float v = (t > 0) ? gld(at + b*256 + d) : 0.f;
        sX[b*648 + 128 + d] = f2bf(v);
      }
      for (int i = tid; i < 8192; i += 256) {           // h_a(t-1)
        int b = i >> 8, d = i & 255;
        float v = (t > 0) ? gld(fHAS + ((size_t)(t-1)*32 + b)*256 + d) : 0.f;
        sX[b*648 + 384 + d] = f2bf(v);
      }
      { int b = tid >> 3, ul = tid & 7;
        sHP[tid] = (t > 0) ? gld(fHAS + ((size_t)(t-1)*32 + b)*256 + j*8 + ul) : 0.f; }
      __syncthreads();
      { // GEMM [32x640]@[640x32]
        const int mt = wv >> 1, nt = wv & 1;
        f32x4 acc = {0.f, 0.f, 0.f, 0.f};
        const unsigned short* xr = sX + (size_t)(mt*16 + (lane&15))*648 + ((lane>>4)*8);
        const unsigned short* wh = sW + (size_t)(nt*16 + (lane&15))*648 + ((lane>>4)*8);
        const unsigned short* wl = wh + 32*648;
        for (int kt = 0; kt < 20; ++kt) {
          bf16x8 a  = *(const bf16x8*)(xr + kt*32);
          bf16x8 bh = *(const bf16x8*)(wh + kt*32);
          bf16x8 bl = *(const bf16x8*)(wl + kt*32);
          acc = __builtin_amdgcn_mfma_f32_16x16x32_bf16(a, bh, acc, 0, 0, 0);
          acc = __builtin_amdgcn_mfma_f32_16x16x32_bf16(a, bl, acc, 0, 0, 0);
        }
        int r0 = mt*16 + ((lane>>4)<<2), c = nt*16 + (lane&15);
        #pragma unroll
        for (int i2 = 0; i2 < 4; ++i2) sOut[(r0+i2)*36 + c] = acc[i2];
      }
      __syncthreads();
      { int b = tid >> 3, ul = tid & 7;
        float z = sigm(sOut[b*36 + ul] + sB[ul]);
        float r = sigm(sOut[b*36 + 8 + ul] + sB[8+ul]);
        float hh = ftanh(sOut[b*36 + 16 + ul] + sB[16+ul] + r*(sOut[b*36 + 24 + ul] + sB[24+ul]));
        float hn = z * sHP[tid] + (1.0f - z) * hh;
        gst(fHAS + ((size_t)t*32 + b)*256 + j*8 + ul, hn);
      }
      set_flag(myflag, (unsigned)(t + 1));
    }
  } else if (bid < 160) {
    // ========== stage Bp: attention partials; q0 combines+publishes ========
    const int idx = bid - 32, b = idx >> 2, q = idx & 3;
    unsigned* myflag = fl + (32 + b*3 + (q - 1)) * 32;   // only used when q>0
    float* sWV  = (float*)smem;            // [50][260]
    float* sMem = (float*)(smem + 52000);  // [50][260]
    float* sV   = (float*)(smem + 104000); // [256]
    float* sHA  = (float*)(smem + 105024); // [256]
    float* sUh  = (float*)(smem + 106048); // [256]
    float* sE   = (float*)(smem + 107072); // [64]
    float* sZ   = (float*)(smem + 107328); // [1]
    float* sCtx = (float*)(smem + 107392); // [256]
    float* sZs  = (float*)(smem + 108416); // [4]
    for (int i = tid; i < 50*256; i += 256) {
      int r = i >> 8, d = i & 255;
      sWV[r*260 + d]  = fWV[((size_t)b*200 + q*50 + r)*256 + d];
      sMem[r*260 + d] = memg[((size_t)b*200 + q*50 + r)*256 + d];
    }
    sV[tid] = Vw[tid];
    __syncthreads();
    for (int t = 0; t < TDEC; ++t) {
      pollwait(fl + (tid & 31)*32, (unsigned)(t + 1), tid < 32);   // A(t) done
      sHA[tid] = gld(fHAS + ((size_t)t*32 + b)*256 + tid);
      __syncthreads();
      { // Uh = h_a[b] @ U  (U read-only: stays L2-hot now)
        float acc = 0.f;
        #pragma unroll 8
        for (int k = 0; k < 256; ++k) acc += sHA[k] * Uw[(size_t)k*256 + tid];
        sUh[tid] = acc; }
      __syncthreads();
      { int r = tid >> 2, qd = tid & 3;
        float part = 0.f;
        if (r < 50) {
          const float* wvp = sWV + r*260 + qd*64;
          const float* uh = sUh + qd*64;
          const float* vv = sV + qd*64;
          #pragma unroll 8
          for (int i2 = 0; i2 < 64; ++i2) part += vv[i2] * ftanh(wvp[i2] + uh[i2]);
        }
        part += __shfl_down(part, 2, 4);
        part += __shfl_down(part, 1, 4);
        if (r < 50 && qd == 0) sE[r] = __expf(part);   // max-free: scores bounded
      }
      __syncthreads();
      if (tid < 64) {
        float e = (tid < 50) ? sE[tid] : 0.f;
        #pragma unroll
        for (int off = 32; off; off >>= 1) e += __shfl_xor(e, off, 64);
        if (tid == 0) sZ[0] = e;
      }
      __syncthreads();
      { float acc = 0.f;
        #pragma unroll 2
        for (int r = 0; r < 50; ++r) acc += sE[r] * sMem[r*260 + tid];
        if (q) gst(fNPq + ((size_t)b*3 + q - 1)*256 + tid, acc);
        else   sCtx[tid] = acc; }
      if (q) {
        if (tid == 0) gst(fZPq + b*3 + q - 1, sZ[0]);
        set_flag(myflag, (unsigned)(t + 1));
      } else {
        // combine: wait 3 siblings(t); fAT slot overwrite gated by C1 >= t-1
        { const unsigned* p; unsigned tg; bool act;
          if (tid < 3)                    { p = fl + (32 + b*3 + tid)*32; tg = (unsigned)(t+1); act = true; }
          else if (tid >= 32 && tid < 64) { p = fl + (160 + tid - 32)*32; tg = (unsigned)(t-1); act = (t >= 2); }
          else                            { p = fl;                       tg = 0u;              act = false; }
          pollwait(p, tg, act);
        }
        if (tid < 3) sZs[tid] = gld(fZPq + b*3 + tid);
        __syncthreads();
        float Zi = 1.0f / (sZ[0] + sZs[0] + sZs[1] + sZs[2]);
        float av = (sCtx[tid] + gld(fNPq + (size_t)(b*3 + 0)*256 + tid)
                             + gld(fNPq + (size_t)(b*3 + 1)*256 + tid)
                             + gld(fNPq + (size_t)(b*3 + 2)*256 + tid)) * Zi;
        gst(fAT + (size_t)(t & 1)*8192 + b*256 + tid, av);
        set_flag(fl + (128 + b)*32, (unsigned)(t + 1));
      }
    }
  } else if (bid < 192) {
    // ================= stage C: proj + GRU1 (8 units) ======================
    const int j = bid - 160;
    unsigned* flagC1 = fl + (160 + j) * 32;
    unsigned* flagC2 = fl + (192 + j) * 32;
    unsigned short* sW1 = (unsigned short*)smem;            // [2][16][520]
    unsigned short* sW2 = (unsigned short*)(smem + 33280);  // [2][32][520]
    unsigned short* sX  = (unsigned short*)(smem + 99840);  // [32][520]
    float* sOut = (float*)(smem + 133120);                  // [32][36]
    float* sPJ  = (float*)(smem + 137728);                  // [32][8]
    float* sH1p = (float*)(smem + 138752);                  // [32][8]
    float* sB   = (float*)(smem + 139776);                  // [5][8]
    {
      const uint4* s1 = (const uint4*)(img + IMGC1_OFF + (size_t)j*2*16*520);
      uint4* d1 = (uint4*)sW1;
      for (int i = tid; i < 33280/16; i += 256) d1[i] = s1[i];
      const uint4* s2 = (const uint4*)(img + IMGC2_OFF + (size_t)j*2*32*520);
      uint4* d2 = (uint4*)sW2;
      for (int i = tid; i < 66560/16; i += 256) d2[i] = s2[i];
      if (tid < 8) {
        int u = j*8 + tid;
        sB[tid]      = B1v[u]       + B1v[768 + u];
        sB[8 + tid]  = B1v[256 + u] + B1v[1024 + u];
        sB[16 + tid] = B1v[512 + u];
        sB[24 + tid] = B1v[1280 + u];
        sB[32 + tid] = pb[u];
      }
    }
    __syncthreads();
    for (int t = 0; t < TDEC; ++t) {
      { // wait: attn(t) final; C2 >= t (fPJ/h1 safety); D >= t-1 (r1 parity)
        const unsigned* p; unsigned tg; bool act;
        if (tid < 32)      { p = fl + (128 + tid)*32;       tg = (unsigned)(t+1); act = true; }
        else if (tid < 64) { p = fl + (192 + tid - 32)*32;  tg = (unsigned)t;     act = (t > 0); }
        else if (tid < 96) { p = fl + (224 + tid - 64)*32;  tg = (unsigned)(t-1); act = (t >= 2); }
        else               { p = fl;                        tg = 0u;              act = false; }
        pollwait(p, tg, act);
      }
      float* at = fAT + (size_t)(t & 1)*8192;
      for (int i = tid; i < 8192; i += 256) {           // attn(t)
        int b = i >> 8, d = i & 255;
        sX[b*520 + d] = f2bf(gld(at + b*256 + d));
      }
      for (int i = tid; i < 8192; i += 256) {           // h_a(t)
        int b = i >> 8, d = i & 255;
        sX[b*520 + 256 + d] = f2bf(gld(fHAS + ((size_t)t*32 + b)*256 + d));
      }
      __syncthreads();
      if (wv < 2) { // GEMM proj: [32x512]@[512x16(8 valid)]
        const int mt = wv;
        f32x4 acc = {0.f, 0.f, 0.f, 0.f};
        const unsigned short* xr = sX + (size_t)(mt*16 + (lane&15))*520 + ((lane>>4)*8);
        const unsigned short* wh = sW1 + (size_t)(lane&15)*520 + ((lane>>4)*8);
        const unsigned short* wl = wh + 16*520;
        for (int kt = 0; kt < 16; ++kt) {
          bf16x8 a  = *(const bf16x8*)(xr + kt*32);
          bf16x8 bh = *(const bf16x8*)(wh + kt*32);
          bf16x8 bl = *(const bf16x8*)(wl + kt*32);
          acc = __builtin_amdgcn_mfma_f32_16x16x32_bf16(a, bh, acc, 0, 0, 0);
          acc = __builtin_amdgcn_mfma_f32_16x16x32_bf16(a, bl, acc, 0, 0, 0);
        }
        int r0 = mt*16 + ((lane>>4)<<2), c = lane & 15;
        #pragma unroll
        for (int i2 = 0; i2 < 4; ++i2) sOut[(r0+i2)*36 + c] = acc[i2];
      }
      __syncthreads();
      { int b = tid >> 3, ul = tid & 7;
        float pj = sOut[b*36 + ul] + sB[32 + ul];
        sPJ[tid] = pj;
        gst(fPJ + (size_t)b*256 + j*8 + ul, pj); }
      set_flag(flagC1, (unsigned)(t + 1));
      pollwait(fl + (160 + (tid & 31))*32, (unsigned)(t + 1), tid < 32);
      for (int i = tid; i < 8192; i += 256) {           // proj(t) full
        int b = i >> 8, d = i & 255;
        sX[b*520 + d] = f2bf(gld(fPJ + (size_t)b*256 + d));
      }
      for (int i = tid; i < 8192; i += 256) {           // h1(t-1)
        int b = i >> 8, d = i & 255;
        sX[b*520 + 256 + d] = f2bf(gld(fH1B + (size_t)(t & 1)*8192 + (size_t)b*256 + d));
      }
      { int b = tid >> 3, ul = tid & 7;
        sH1p[tid] = gld(fH1B + (size_t)(t & 1)*8192 + (size_t)b*256 + j*8 + ul); }
      __syncthreads();
      { // GEMM GRU1
        const int mt = wv >> 1, nt = wv & 1;
        f32x4 acc = {0.f, 0.f, 0.f, 0.f};
        const unsigned short* xr = sX + (size_t)(mt*16 + (lane&15))*520 + ((lane>>4)*8);
        const unsigned short* wh = sW2 + (size_t)(nt*16 + (lane&15))*520 + ((lane>>4)*8);
        const unsigned short* wl = wh + 32*520;
        for (int kt = 0; kt < 16; ++kt) {
          bf16x8 a  = *(const bf16x8*)(xr + kt*32);
          bf16x8 bh = *(const bf16x8*)(wh + kt*32);
          bf16x8 bl = *(const bf16x8*)(wl + kt*32);
          acc = __builtin_amdgcn_mfma_f32_16x16x32_bf16(a, bh, acc, 0, 0, 0);
          acc = __builtin_amdgcn_mfma_f32_16x16x32_bf16(a, bl, acc, 0, 0, 0);
        }
        int r0 = mt*16 + ((lane>>4)<<2), c = nt*16 + (lane&15);
        #pragma unroll
        for (int i2 = 0; i2 < 4; ++i2) sOut[(r0+i2)*36 + c] = acc[i2];
      }
      __syncthreads();
      { int b = tid >> 3, ul = tid & 7;
        float z = sigm(sOut[b*36 + ul] + sB[ul]);
        float r = sigm(sOut[b*36 + 8 + ul] + sB[8+ul]);
        float hh = ftanh(sOut[b*36 + 16 + ul] + sB[16+ul] + r*(sOut[b*36 + 24 + ul] + sB[24+ul]));
        float hn = z * sH1p[tid] + (1.0f - z) * hh;
        gst(fH1B + (size_t)((t+1) & 1)*8192 + (size_t)b*256 + j*8 + ul, hn);
        gst(fR1B + (size_t)(t & 1)*8192 + (size_t)b*256 + j*8 + ul, sPJ[tid] + hn);
      }
      set_flag(flagC2, (unsigned)(t + 1));
    }
  } else {
    // ================= stage D: GRU2 (8 units) =============================
    const int j = bid - 192;
    unsigned* myflag = fl + (224 + j) * 32;
    unsigned short* sW = (unsigned short*)smem;            // [2][32][520]
    unsigned short* sX = (unsigned short*)(smem + 66560);  // [32][520]
    float* sOut = (float*)(smem + 99840);                  // [32][36]
    float* sR1f = (float*)(smem + 104448);                 // [32][8]
    float* sH2p = (float*)(smem + 105472);                 // [32][8]
    float* sB   = (float*)(smem + 106496);                 // [4][8]
    {
      const uint4* s2 = (const uint4*)(img + IMGD_OFF + (size_t)j*2*32*520);
      uint4* d2 = (uint4*)sW;
      for (int i = tid; i < 66560/16; i += 256) d2[i] = s2[i];
      if (tid < 8) {
        int u = j*8 + tid;
        sB[tid]      = B2v[u]       + B2v[768 + u];
        sB[8 + tid]  = B2v[256 + u] + B2v[1024 + u];
        sB[16 + tid] = B2v[512 + u];
        sB[24 + tid] = B2v[1280 + u];
      }
    }
    __syncthreads();
    for (int t = 0; t < TDEC; ++t) {
      { const unsigned* p; unsigned tg; bool act;
        if (tid < 32)      { p = fl + (192 + tid)*32;       tg = (unsigned)(t+1); act = true; }
        else if (tid < 64) { p = fl + (224 + tid - 32)*32;  tg = (unsigned)t;     act = (t > 0); }
        else               { p = fl;                        tg = 0u;              act = false; }
        pollwait(p, tg, act);
      }
      for (int i = tid; i < 8192; i += 256) {           // r1(t)
        int b = i >> 8, d = i & 255;
        sX[b*520 + d] = f2bf(gld(fR1B + (size_t)(t & 1)*8192 + (size_t)b*256 + d));
      }
      for (int i = tid; i < 8192; i += 256) {           // h2(t-1)
        int b = i >> 8, d = i & 255;
        sX[b*520 + 256 + d] = f2bf(gld(fH2B + (size_t)(t & 1)*8192 + (size_t)b*256 + d));
      }
      { int b = tid >> 3, ul = tid & 7;
        sR1f[tid] = gld(fR1B + (size_t)(t & 1)*8192 + (size_t)b*256 + j*8 + ul);
        sH2p[tid] = gld(fH2B + (size_t)(t & 1)*8192 + (size_t)b*256 + j*8 + ul); }
      __syncthreads();
      { const int mt = wv >> 1, nt = wv & 1;
        f32x4 acc = {0.f, 0.f, 0.f, 0.f};
        const unsigned short* xr = sX + (size_t)(mt*16 + (lane&15))*520 + ((lane>>4)*8);
        const unsigned short* wh = sW + (size_t)(nt*16 + (lane&15))*520 + ((lane>>4)*8);
        const unsigned short* wl = wh + 32*520;
        for (int kt = 0; kt < 16; ++kt) {
          bf16x8 a  = *(const bf16x8*)(xr + kt*32);
          bf16x8 bh = *(const bf16x8*)(wh + kt*32);
          bf16x8 bl = *(const bf16x8*)(wl + kt*32);
          acc = __builtin_amdgcn_mfma_f32_16x16x32_bf16(a, bh, acc, 0, 0, 0);
          acc = __builtin_amdgcn_mfma_f32_16x16x32_bf16(a, bl, acc, 0, 0, 0);
        }
        int r0 = mt*16 + ((lane>>4)<<2), c = nt*16 + (lane&15);
        #pragma unroll
        for (int i2 = 0; i2 < 4; ++i2) sOut[(r0+i2)*36 + c] = acc[i2];
      }
      __syncthreads();
      { int b = tid >> 3, ul = tid & 7;
        float z = sigm(sOut[b*36 + ul] + sB[ul]);
        float r = sigm(sOut[b*36 + 8 + ul] + sB[8+ul]);
        float hh = ftanh(sOut[b*36 + 16 + ul] + sB[16+ul] + r*(sOut[b*36 + 24 + ul] + sB[24+ul]));
        float hn = z * sH2p[tid] + (1.0f - z) * hh;
        gst(fH2B + (size_t)((t+1) & 1)*8192 + (size_t)b*256 + j*8 + ul, hn);
        fR2S[((size_t)t*32 + b)*256 + j*8 + ul] = sR1f[tid] + hn;   // read by k_out only
      }
      set_flag(myflag, (unsigned)(t + 1));
    }
  }
}

// ---------------------------------------------------------------------------
__global__ __launch_bounds__(256) void k_wv(
    const float* __restrict__ mem, const float* __restrict__ W, float* __restrict__ wv)
{
  const int tile = blockIdx.x, b = blockIdx.y;
  const int t0 = tile * 8, tid = threadIdx.x;
  __shared__ float rows[2048];
  for (int i = tid; i < 2048; i += 256) rows[i] = mem[((size_t)b*TENC + t0)*256 + i];
  __syncthreads();
  float acc[8] = {0,0,0,0,0,0,0,0};
  for (int k = 0; k < 256; ++k) {
    float w = W[(size_t)k*256 + tid];
    #pragma unroll
    for (int tt = 0; tt < 8; ++tt) acc[tt] += rows[tt*256 + k] * w;
  }
  #pragma unroll
  for (int tt = 0; tt < 8; ++tt) wv[((size_t)b*TENC + t0 + tt)*256 + tid] = acc[tt];
}

__global__ __launch_bounds__(256) void k_prenet(
    const float* __restrict__ x, const float* __restrict__ w1, const float* __restrict__ b1,
    const float* __restrict__ w2, const float* __restrict__ b2, float* __restrict__ q2)
{
  const int tile = blockIdx.x, b = blockIdx.y;
  const int t0 = tile * 4, tid = threadIdx.x;
  __shared__ float xr[320];
  __shared__ float q1[1024];
  for (int i = tid; i < 320; i += 256) {
    int tt = i / 80, k = i - tt*80;
    xr[i] = x[((size_t)b*TDEC + t0 + tt)*80 + k];
  }
  __syncthreads();
  {
    float a0 = 0.f, a1 = 0.f, a2 = 0.f, a3 = 0.f;
    for (int k = 0; k < 80; ++k) {
      float w = w1[(size_t)k*256 + tid];
      a0 += xr[k]*w; a1 += xr[80+k]*w; a2 += xr[160+k]*w; a3 += xr[240+k]*w;
    }
    float bb = b1[tid];
    q1[tid]       = fmaxf(a0 + bb, 0.f);
    q1[256 + tid] = fmaxf(a1 + bb, 0.f);
    q1[512 + tid] = fmaxf(a2 + bb, 0.f);
    q1[768 + tid] = fmaxf(a3 + bb, 0.f);
  }
  __syncthreads();
  {
    const int jj = tid & 127, tp = tid >> 7;
    float c0 = 0.f, c1 = 0.f;
    for (int k = 0; k < 256; ++k) {
      float w = w2[(size_t)k*128 + jj];
      c0 += q1[(2*tp)*256 + k] * w;
      c1 += q1[(2*tp + 1)*256 + k] * w;
    }
    float bb = b2[jj];
    q2[(((size_t)t0 + 2*tp)*32 + b)*128 + jj]     = fmaxf(c0 + bb, 0.f);
    q2[(((size_t)t0 + 2*tp + 1)*32 + b)*128 + jj] = fmaxf(c1 + bb, 0.f);
  }
}

__global__ __launch_bounds__(128) void k_out(
    const float* __restrict__ r2, const float* __restrict__ wo,
    const float* __restrict__ bo, float* __restrict__ out)
{
  const int tb = blockIdx.x;
  const int t = tb >> 5, b = tb & 31, tid = threadIdx.x;
  __shared__ float row[256];
  for (int i = tid; i < 256; i += 128) row[i] = r2[(size_t)tb*256 + i];
  __syncthreads();
  if (tid < 80) {
    float acc = bo[tid];
    #pragma unroll 4
    for (int k = 0; k < 256; ++k) acc += row[k] * wo[(size_t)k*80 + tid];
    out[((size_t)b*TDEC + t)*80 + tid] = acc;
  }
}

// ---------------------------------------------------------------------------
extern "C" void kernel_launch(void* const* d_in, const int* in_sizes, int n_in,
                              void* d_out, int out_size, void* d_ws, size_t ws_size,
                              hipStream_t stream)
{
  const float* mem = (const float*)d_in[0];
  const float* dec = (const float*)d_in[1];
  const float* w1  = (const float*)d_in[2];
  const float* b1  = (const float*)d_in[3];
  const float* w2  = (const float*)d_in[4];
  const float* b2  = (const float*)d_in[5];
  const float* aK  = (const float*)d_in[6];
  const float* aRK = (const float*)d_in[7];
  const float* aB  = (const float*)d_in[8];
  const float* W   = (const float*)d_in[9];
  const float* U   = (const float*)d_in[10];
  const float* V   = (const float*)d_in[11];
  const float* Wp  = (const float*)d_in[12];
  const float* pb  = (const float*)d_in[13];
  const float* K1  = (const float*)d_in[14];
  const float* RK1 = (const float*)d_in[15];
  const float* B1v = (const float*)d_in[16];
  const float* K2  = (const float*)d_in[17];
  const float* RK2 = (const float*)d_in[18];
  const float* B2v = (const float*)d_in[19];
  const float* Wo  = (const float*)d_in[20];
  const float* bo  = (const float*)d_in[21];
  float* ws  = (float*)d_ws;
  float* out = (float*)d_out;

  hipMemsetAsync(ws, 0, (size_t)ZERO_FLOATS * sizeof(float), stream);
  k_prep<<<dim3(2592, 4), 256, 0, stream>>>(aK, aRK, Wp, K1, RK1, K2, RK2,
                                            (unsigned short*)(ws + O_IMG));
  k_wv<<<dim3(25, 32), 256, 0, stream>>>(mem, W, ws + O_WV);
  k_prenet<<<dim3(50, 32), 256, 0, stream>>>(dec, w1, b1, w2, b2, ws + O_Q2);
  k_scan8<<<224, 256, 0, stream>>>(mem, aB, U, V, pb, B1v, B2v, ws);
  k_out<<<6400, 128, 0, stream>>>(ws + O_R2S, Wo, bo, out);
}